// Round 1
// baseline (489.534 us; speedup 1.0000x reference)
//
#include <hip/hip_runtime.h>
#include <hip/hip_bf16.h>

// Problem constants
#define TT 512   // T
#define BB 128   // B
#define HH 512   // H
#define NFC 128  // NF
// FS = 5

typedef short v8s __attribute__((ext_vector_type(8)));
typedef float v4f __attribute__((ext_vector_type(4)));

__device__ __forceinline__ unsigned short f2bf(float x) {
    unsigned u = __float_as_uint(x);
    unsigned r = (u + 0x7fffu + ((u >> 16) & 1u)) >> 16;
    return (unsigned short)r;
}

// ---------------------------------------------------------------------------
// Kernel 0a: build stacked weight matrix, bf16, M=2048 x K=512 row-major.
// s = f*16 + slice; slice in [0,15): (w,j) enumeration, slice 15 = zero pad.
// base[w] = {0,1,3,6,10} (1-indexed w).
// ---------------------------------------------------------------------------
__global__ void build_w(const float* __restrict__ w1, const float* __restrict__ w2,
                        const float* __restrict__ w3, const float* __restrict__ w4,
                        const float* __restrict__ w5, unsigned short* __restrict__ Wg) {
    int idx = blockIdx.x * 256 + threadIdx.x;   // 2048*512 = 1,048,576
    int s = idx >> 9, h = idx & 511;
    int f = s >> 4, sl = s & 15;
    float v = 0.f;
    if (sl < 15) {
        int w, j;
        if (sl < 1)       { w = 1; j = sl; }
        else if (sl < 3)  { w = 2; j = sl - 1; }
        else if (sl < 6)  { w = 3; j = sl - 3; }
        else if (sl < 10) { w = 4; j = sl - 6; }
        else              { w = 5; j = sl - 10; }
        const float* wp = (w == 1) ? w1 : (w == 2) ? w2 : (w == 3) ? w3 : (w == 4) ? w4 : w5;
        v = wp[f * (HH * w) + h * w + j];  // conv_w{w}[f,0,h,j]
    }
    Wg[idx] = f2bf(v);
}

// ---------------------------------------------------------------------------
// Kernel 0b: gather X_all, layout [n][h] bf16, n = b*512 + l, row len 512.
// X[b][h,l] = enc[(h*L+l)>>9, b, (h*L+l)&511] for l < L else 0.
// Coalesced reads (l-contiguous) + LDS transpose + coalesced writes (h-contig).
// ---------------------------------------------------------------------------
__global__ void gather_x(const float* __restrict__ enc, const int* __restrict__ lengths,
                         unsigned short* __restrict__ Xg) {
    __shared__ float tile[64 * 65];
    int bi = blockIdx.x;              // 128 b * 8 lc * 8 hc = 8192
    int b = bi >> 6;
    int lc = (bi >> 3) & 7;
    int hc = bi & 7;
    int L = lengths[b];
    int l0 = lc * 64, h0 = hc * 64;
    int tid = threadIdx.x;            // 256
    int lx = tid & 63;
    int hq = tid >> 6;                // 0..3
    #pragma unroll
    for (int r = 0; r < 16; ++r) {
        int hl = hq * 16 + r;         // local h
        int l = l0 + lx;
        float v = 0.f;
        if (l < L) {
            int i = (h0 + hl) * L + l;
            v = enc[(i >> 9) * (BB * HH) + b * HH + (i & 511)];
        }
        tile[hl * 65 + lx] = v;
    }
    __syncthreads();
    int hO = tid & 63;
    #pragma unroll
    for (int r = 0; r < 16; ++r) {
        int lloc = (tid >> 6) * 16 + r;
        int n = b * 512 + l0 + lloc;
        Xg[n * 512 + h0 + hO] = f2bf(tile[hO * 65 + lloc]);
    }
}

// ---------------------------------------------------------------------------
// Kernel 0c: zero the pool accumulators.
// ---------------------------------------------------------------------------
__global__ void zero_pools(float* __restrict__ pools) {
    int i = blockIdx.x * 256 + threadIdx.x;
    if (i < BB * 5 * NFC) pools[i] = 0.f;
}

// ---------------------------------------------------------------------------
// Kernel 1: main fused GEMM + epilogue.
// Block tile: 128 (M, = 8 filter groups of 16 slices) x 128 (N, t-range of one b).
// 4 waves, each 64x64 (4x4 MFMA subtiles of 16x16x32 bf16).
// Epilogue: acc -> LDS Gs (2 phases of 64 rows), shift-add over j, relu+bias,
// mask t < Leff-w+1, max over t, atomicMax into pools. Boundary cols (0..3 /
// 124..127) stored raw to strips for the cleanup kernel.
// ---------------------------------------------------------------------------
__global__ __launch_bounds__(256, 3)
void conv_gemm(const unsigned short* __restrict__ Wg, const unsigned short* __restrict__ Xg,
               const int* __restrict__ lengths,
               const float* __restrict__ cb1, const float* __restrict__ cb2,
               const float* __restrict__ cb3, const float* __restrict__ cb4,
               const float* __restrict__ cb5,
               float* __restrict__ pools, float* __restrict__ strips) {
    __shared__ unsigned short ldsA[128 * 32];   // 8 KB
    __shared__ unsigned short ldsB[128 * 32];   // 8 KB
    __shared__ float Gs[64 * 129];              // 33 KB (padded rows: no bank conflict)

    int bi = blockIdx.x;                 // 8192 = 128 b * 16 mtile * 4 tt
    int b = bi >> 6;
    int mtile = (bi >> 2) & 15;
    int tt = bi & 3;
    int tid = threadIdx.x;
    int wid = tid >> 6, lane = tid & 63;
    int wm = wid >> 1, wn = wid & 1;
    int llo = lane & 15, quad = lane >> 4;

    int m0 = mtile * 128;
    int nb0 = b * 512 + tt * 128;

    v4f acc[4][4];
    #pragma unroll
    for (int i = 0; i < 4; ++i)
        #pragma unroll
        for (int j = 0; j < 4; ++j) acc[i][j] = v4f{0.f, 0.f, 0.f, 0.f};

    // staging: wave wid covers rows [wid*32, wid*32+32) in 2 instructions of 16 rows
    int srow = lane >> 2;     // 0..15
    int schunk = lane & 3;    // 16B chunk within the 64B k-window of a row
    const unsigned short* gA = Wg + (m0 + wid * 32 + srow) * 512 + schunk * 8;
    const unsigned short* gB = Xg + (nb0 + wid * 32 + srow) * 512 + schunk * 8;

    #pragma unroll 1
    for (int kt = 0; kt < 16; ++kt) {
        int ko = kt * 32;
        #pragma unroll
        for (int q = 0; q < 2; ++q) {
            __builtin_amdgcn_global_load_lds(
                (const __attribute__((address_space(1))) unsigned int*)(gA + q * (16 * 512) + ko),
                (__attribute__((address_space(3))) unsigned int*)&ldsA[(wid * 32 + q * 16) * 32],
                16, 0, 0);
            __builtin_amdgcn_global_load_lds(
                (const __attribute__((address_space(1))) unsigned int*)(gB + q * (16 * 512) + ko),
                (__attribute__((address_space(3))) unsigned int*)&ldsB[(wid * 32 + q * 16) * 32],
                16, 0, 0);
        }
        __syncthreads();
        v8s Af[4], Bf[4];
        #pragma unroll
        for (int mi = 0; mi < 4; ++mi)
            Af[mi] = *(const v8s*)&ldsA[(wm * 64 + mi * 16 + llo) * 32 + quad * 8];
        #pragma unroll
        for (int ni = 0; ni < 4; ++ni)
            Bf[ni] = *(const v8s*)&ldsB[(wn * 64 + ni * 16 + llo) * 32 + quad * 8];
        #pragma unroll
        for (int mi = 0; mi < 4; ++mi)
            #pragma unroll
            for (int ni = 0; ni < 4; ++ni)
                acc[mi][ni] = __builtin_amdgcn_mfma_f32_16x16x32_bf16(Af[mi], Bf[ni], acc[mi][ni], 0, 0, 0);
        __syncthreads();
    }

    // ---- epilogue ----
    int L = lengths[b];
    int Leff = L > 5 ? L : 5;
    const int basew[6] = {0, 0, 1, 3, 6, 10};
    long sbase = (long)(((b * 4 + tt) * 16 + mtile) * 128) * 8;

    #pragma unroll 1
    for (int phase = 0; phase < 2; ++phase) {
        if (wm == phase) {
            // C/D layout: col = lane&15, row = quad*4 + reg  [verified m89/m91]
            #pragma unroll
            for (int mi = 0; mi < 4; ++mi)
                #pragma unroll
                for (int ni = 0; ni < 4; ++ni)
                    #pragma unroll
                    for (int r = 0; r < 4; ++r)
                        Gs[(mi * 16 + quad * 4 + r) * 129 + wn * 64 + ni * 16 + llo] = acc[mi][ni][r];
        }
        __syncthreads();
        // boundary strips: slots 0..3 = cols 0..3 (head), 4..7 = cols 124..127 (tail)
        {
            int row = tid >> 3, c = tid & 7;
            int col = (c < 4) ? c : (120 + c);
            #pragma unroll
            for (int rr = 0; rr < 2; ++rr) {
                int r2 = row + rr * 32;
                strips[sbase + (phase * 64 + r2) * 8 + c] = Gs[r2 * 129 + col];
            }
        }
        // pooling: wave wid handles filter group fl = wid of this phase
        {
            int fl = wid;
            int f = mtile * 8 + phase * 4 + fl;
            #pragma unroll
            for (int w = 1; w <= 5; ++w) {
                float bias = (w == 1 ? cb1 : w == 2 ? cb2 : w == 3 ? cb3 : w == 4 ? cb4 : cb5)[f];
                int limt = 128 - w;                    // complete-sum-in-tile bound
                int limv = Leff - w + 1 - tt * 128;    // validity bound (tile-local)
                float vmax = -1.f;
                #pragma unroll
                for (int half = 0; half < 2; ++half) {
                    int t = half * 64 + lane;
                    if (t <= limt && t < limv) {
                        float s = 0.f;
                        #pragma unroll
                        for (int j = 0; j < w; ++j)
                            s += Gs[(fl * 16 + basew[w] + j) * 129 + t + j];
                        s += bias;
                        s = fmaxf(s, 0.f);
                        vmax = fmaxf(vmax, s);
                    }
                }
                #pragma unroll
                for (int off = 32; off >= 1; off >>= 1)
                    vmax = fmaxf(vmax, __shfl_xor(vmax, off));
                if (lane == 0 && vmax >= 0.f)
                    atomicMax((int*)&pools[(b * 5 + (w - 1)) * NFC + f], __float_as_int(vmax));
            }
        }
        __syncthreads();
    }
}

// ---------------------------------------------------------------------------
// Kernel 2: boundary cleanup — pooled outputs whose conv window crosses a
// 128-col tile boundary (t_local in [129-w, 127], tiles 0..2), from strips.
// ---------------------------------------------------------------------------
__global__ void cleanup(const float* __restrict__ strips, const int* __restrict__ lengths,
                        const float* __restrict__ cb2, const float* __restrict__ cb3,
                        const float* __restrict__ cb4, const float* __restrict__ cb5,
                        float* __restrict__ pools) {
    int idx = blockIdx.x * 256 + threadIdx.x;  // 128*16*8 = 16384
    if (idx >= 16384) return;
    int b = idx >> 7;
    int mtile = (idx >> 3) & 15;
    int fl = idx & 7;
    int L = lengths[b];
    int Leff = L > 5 ? L : 5;
    int f = mtile * 8 + fl;
    const int basew[6] = {0, 0, 1, 3, 6, 10};
    for (int t2 = 0; t2 < 3; ++t2) {
        const float* s0 = strips + (long)(((b * 4 + t2) * 16 + mtile) * 128) * 8;
        const float* s1 = strips + (long)(((b * 4 + t2 + 1) * 16 + mtile) * 128) * 8;
        #pragma unroll
        for (int w = 2; w <= 5; ++w) {
            float bias = (w == 2 ? cb2 : w == 3 ? cb3 : w == 4 ? cb4 : cb5)[f];
            float best = -1.f;
            for (int t = 129 - w; t <= 127; ++t) {
                int tg = t2 * 128 + t;
                if (tg >= Leff - w + 1) continue;
                float s = 0.f;
                #pragma unroll
                for (int j = 0; j < w; ++j) {
                    int c = t + j;
                    int row = fl * 16 + basew[w] + j;
                    s += (c <= 127) ? s0[row * 8 + (c - 120)] : s1[row * 8 + (c - 128)];
                }
                s += bias;
                s = fmaxf(s, 0.f);
                best = fmaxf(best, s);
            }
            if (best >= 0.f)
                atomicMax((int*)&pools[(b * 5 + (w - 1)) * NFC + f], __float_as_int(best));
        }
    }
}

// ---------------------------------------------------------------------------
// Kernel 3a: collapse fc2∘fc1 (no activation between them) into v[640], c.
// ---------------------------------------------------------------------------
__global__ void fc_combine(const float* __restrict__ fc1w, const float* __restrict__ fc1b,
                           const float* __restrict__ fc2w, const float* __restrict__ fc2b,
                           float* __restrict__ v) {
    int tid = threadIdx.x;
    for (int k = tid; k < 640; k += 256) {
        float s = 0.f;
        for (int o = 0; o < 100; ++o) s += fc2w[o] * fc1w[o * 640 + k];
        v[k] = s;
    }
    if (tid == 0) {
        float c = fc2b[0];
        for (int o = 0; o < 100; ++o) c += fc2w[o] * fc1b[o];
        v[640] = c;
    }
}

// ---------------------------------------------------------------------------
// Kernel 3b: per-batch dot(feat, v) + c -> sigmoid.
// feat[b][k] = pools[b][w][f] with k = w*128+f (matches concat order).
// ---------------------------------------------------------------------------
__global__ void head(const float* __restrict__ pools, const float* __restrict__ v,
                     float* __restrict__ out) {
    int b = blockIdx.x;
    int tid = threadIdx.x;
    float s = 0.f;
    for (int k = tid; k < 640; k += 256) s += pools[b * 640 + k] * v[k];
    __shared__ float red[256];
    red[tid] = s;
    __syncthreads();
    for (int st = 128; st; st >>= 1) {
        if (tid < st) red[tid] += red[tid + st];
        __syncthreads();
    }
    if (tid == 0) out[b] = 1.f / (1.f + expf(-(red[0] + v[640])));
}

// ---------------------------------------------------------------------------
extern "C" void kernel_launch(void* const* d_in, const int* in_sizes, int n_in,
                              void* d_out, int out_size, void* d_ws, size_t ws_size,
                              hipStream_t stream) {
    const float* enc  = (const float*)d_in[0];
    const int* lens   = (const int*)d_in[1];
    const float* w1   = (const float*)d_in[2];
    const float* b1   = (const float*)d_in[3];
    const float* w2   = (const float*)d_in[4];
    const float* b2   = (const float*)d_in[5];
    const float* w3   = (const float*)d_in[6];
    const float* b3   = (const float*)d_in[7];
    const float* w4   = (const float*)d_in[8];
    const float* b4   = (const float*)d_in[9];
    const float* w5   = (const float*)d_in[10];
    const float* b5   = (const float*)d_in[11];
    const float* fc1w = (const float*)d_in[12];
    const float* fc1b = (const float*)d_in[13];
    const float* fc2w = (const float*)d_in[14];
    const float* fc2b = (const float*)d_in[15];
    float* out = (float*)d_out;

    // workspace layout
    unsigned short* Xg = (unsigned short*)d_ws;          // 33,554,432 ushorts (64 MB)
    unsigned short* Wg = Xg + 33554432;                  // 1,048,576 ushorts (2 MB)
    float* strips = (float*)(Wg + 1048576);              // 8,388,608 floats (32 MB)
    float* pools  = strips + 8388608;                    // 81,920 floats
    float* vbuf   = pools + 81920;                       // 641 floats

    build_w<<<4096, 256, 0, stream>>>(w1, w2, w3, w4, w5, Wg);
    gather_x<<<8192, 256, 0, stream>>>(enc, lens, Xg);
    zero_pools<<<320, 256, 0, stream>>>(pools);
    conv_gemm<<<8192, 256, 0, stream>>>(Wg, Xg, lens, b1, b2, b3, b4, b5, pools, strips);
    cleanup<<<64, 256, 0, stream>>>(strips, lens, b2, b3, b4, b5, pools);
    fc_combine<<<1, 256, 0, stream>>>(fc1w, fc1b, fc2w, fc2b, vbuf);
    head<<<128, 256, 0, stream>>>(pools, vbuf, out);
}

// Round 2
// 447.433 us; speedup vs baseline: 1.0941x; 1.0941x over previous
//
#include <hip/hip_runtime.h>
#include <hip/hip_bf16.h>

// Problem constants
#define TT 512   // T
#define BB 128   // B
#define HH 512   // H
#define NFC 128  // NF
// FS = 5

typedef short v8s __attribute__((ext_vector_type(8)));
typedef float v4f __attribute__((ext_vector_type(4)));

__device__ __forceinline__ unsigned short f2bf(float x) {
    unsigned u = __float_as_uint(x);
    unsigned r = (u + 0x7fffu + ((u >> 16) & 1u)) >> 16;
    return (unsigned short)r;
}

// ---------------------------------------------------------------------------
// Kernel 0: fused prep.
// blocks [0,4096): build stacked weight matrix Wg, bf16, M=2048 x K=512.
//   s = f*16 + slice; slice in [0,15): (w,j) enumeration, slice 15 = pad.
// blocks [4096,4416): zero pools.
// block 4416: collapse fc2∘fc1 into v[640] + c (no activation between them).
// ---------------------------------------------------------------------------
__global__ void prep(const float* __restrict__ w1, const float* __restrict__ w2,
                     const float* __restrict__ w3, const float* __restrict__ w4,
                     const float* __restrict__ w5, unsigned short* __restrict__ Wg,
                     float* __restrict__ pools,
                     const float* __restrict__ fc1w, const float* __restrict__ fc1b,
                     const float* __restrict__ fc2w, const float* __restrict__ fc2b,
                     float* __restrict__ v) {
    int blk = blockIdx.x;
    int tid = threadIdx.x;
    if (blk < 4096) {
        int idx = blk * 256 + tid;   // 2048*512 = 1,048,576
        int s = idx >> 9, h = idx & 511;
        int f = s >> 4, sl = s & 15;
        float val = 0.f;
        if (sl < 15) {
            int w, j;
            if (sl < 1)       { w = 1; j = sl; }
            else if (sl < 3)  { w = 2; j = sl - 1; }
            else if (sl < 6)  { w = 3; j = sl - 3; }
            else if (sl < 10) { w = 4; j = sl - 6; }
            else              { w = 5; j = sl - 10; }
            const float* wp = (w == 1) ? w1 : (w == 2) ? w2 : (w == 3) ? w3 : (w == 4) ? w4 : w5;
            val = wp[f * (HH * w) + h * w + j];  // conv_w{w}[f,0,h,j]
        }
        Wg[idx] = f2bf(val);
    } else if (blk < 4416) {
        int i = (blk - 4096) * 256 + tid;
        if (i < BB * 5 * NFC) pools[i] = 0.f;
    } else {
        for (int k = tid; k < 640; k += 256) {
            float s = 0.f;
            for (int o = 0; o < 100; ++o) s += fc2w[o] * fc1w[o * 640 + k];
            v[k] = s;
        }
        if (tid == 0) {
            float c = fc2b[0];
            for (int o = 0; o < 100; ++o) c += fc2w[o] * fc1b[o];
            v[640] = c;
        }
    }
}

// ---------------------------------------------------------------------------
// Kernel 0b: gather X_all, layout [n][h] bf16, n = b*512 + l, row len 512.
// X[b][h,l] = enc[(h*L+l)>>9, b, (h*L+l)&511] for l < L else 0.
// Coalesced reads (l-contiguous) + LDS transpose + coalesced writes (h-contig).
// ---------------------------------------------------------------------------
__global__ void gather_x(const float* __restrict__ enc, const int* __restrict__ lengths,
                         unsigned short* __restrict__ Xg) {
    __shared__ float tile[64 * 65];
    int bi = blockIdx.x;              // 128 b * 8 lc * 8 hc = 8192
    int b = bi >> 6;
    int lc = (bi >> 3) & 7;
    int hc = bi & 7;
    int L = lengths[b];
    int l0 = lc * 64, h0 = hc * 64;
    int tid = threadIdx.x;            // 256
    int lx = tid & 63;
    int hq = tid >> 6;                // 0..3
    #pragma unroll
    for (int r = 0; r < 16; ++r) {
        int hl = hq * 16 + r;         // local h
        int l = l0 + lx;
        float v = 0.f;
        if (l < L) {
            int i = (h0 + hl) * L + l;
            v = enc[(i >> 9) * (BB * HH) + b * HH + (i & 511)];
        }
        tile[hl * 65 + lx] = v;
    }
    __syncthreads();
    int hO = tid & 63;
    #pragma unroll
    for (int r = 0; r < 16; ++r) {
        int lloc = (tid >> 6) * 16 + r;
        int n = b * 512 + l0 + lloc;
        Xg[n * 512 + h0 + hO] = f2bf(tile[hO * 65 + lloc]);
    }
}

// ---------------------------------------------------------------------------
// Kernel 1: main fused GEMM + epilogue.
// Block tile: 128 (M, = 8 filter groups of 16 slices) x 128 (N, t-range of one b).
// 4 waves, each 64x64 (4x4 MFMA subtiles of 16x16x32 bf16).
// LDS bank-conflict avoidance: XOR chunk swizzle — global 16B chunk q of a
// 64B k-window lands at physical slot p = q ^ ((row>>1)&3). Staging permutes
// the per-lane GLOBAL address (LDS dest must stay lane-contiguous, m104);
// fragment reads use p = quad ^ ((llo>>1)&3) -> 2-way (free) instead of 8-way.
// Gs (epilogue scratch) aliases ldsA/ldsB (disjoint lifetimes) -> 33 KB LDS
// -> 4 blocks/CU instead of 3.
// ---------------------------------------------------------------------------
__global__ __launch_bounds__(256, 4)
void conv_gemm(const unsigned short* __restrict__ Wg, const unsigned short* __restrict__ Xg,
               const int* __restrict__ lengths,
               const float* __restrict__ cb1, const float* __restrict__ cb2,
               const float* __restrict__ cb3, const float* __restrict__ cb4,
               const float* __restrict__ cb5,
               float* __restrict__ pools, float* __restrict__ strips) {
    __shared__ __align__(16) char smem[64 * 129 * 4];      // 33024 B
    unsigned short* ldsA = (unsigned short*)smem;           // 8 KB (K-loop only)
    unsigned short* ldsB = (unsigned short*)(smem + 8192);  // 8 KB (K-loop only)
    float* Gs = (float*)smem;                               // 64*129 (epilogue only)

    int bi = blockIdx.x;                 // 8192 = 128 b * 16 mtile * 4 tt
    int b = bi >> 6;
    int mtile = (bi >> 2) & 15;
    int tt = bi & 3;
    int tid = threadIdx.x;
    int wid = tid >> 6, lane = tid & 63;
    int wm = wid >> 1, wn = wid & 1;
    int llo = lane & 15, quad = lane >> 4;
    int psw = quad ^ ((llo >> 1) & 3);   // swizzled physical chunk for frag reads

    int m0 = mtile * 128;
    int nb0 = b * 512 + tt * 128;

    v4f acc[4][4];
    #pragma unroll
    for (int i = 0; i < 4; ++i)
        #pragma unroll
        for (int j = 0; j < 4; ++j) acc[i][j] = v4f{0.f, 0.f, 0.f, 0.f};

    // staging: wave wid covers rows [wid*32, wid*32+32) in 2 instructions of 16 rows
    int srow = lane >> 2;                           // 0..15
    int gchunk = (lane & 3) ^ ((lane >> 3) & 3);    // global chunk for physical slot lane&3
    const unsigned short* gA = Wg + (m0 + wid * 32 + srow) * 512 + gchunk * 8;
    const unsigned short* gB = Xg + (nb0 + wid * 32 + srow) * 512 + gchunk * 8;

    #pragma unroll 1
    for (int kt = 0; kt < 16; ++kt) {
        int ko = kt * 32;
        #pragma unroll
        for (int q = 0; q < 2; ++q) {
            __builtin_amdgcn_global_load_lds(
                (const __attribute__((address_space(1))) unsigned int*)(gA + q * (16 * 512) + ko),
                (__attribute__((address_space(3))) unsigned int*)&ldsA[(wid * 32 + q * 16) * 32],
                16, 0, 0);
            __builtin_amdgcn_global_load_lds(
                (const __attribute__((address_space(1))) unsigned int*)(gB + q * (16 * 512) + ko),
                (__attribute__((address_space(3))) unsigned int*)&ldsB[(wid * 32 + q * 16) * 32],
                16, 0, 0);
        }
        __syncthreads();
        v8s Af[4], Bf[4];
        #pragma unroll
        for (int mi = 0; mi < 4; ++mi)
            Af[mi] = *(const v8s*)&ldsA[(wm * 64 + mi * 16 + llo) * 32 + psw * 8];
        #pragma unroll
        for (int ni = 0; ni < 4; ++ni)
            Bf[ni] = *(const v8s*)&ldsB[(wn * 64 + ni * 16 + llo) * 32 + psw * 8];
        #pragma unroll
        for (int mi = 0; mi < 4; ++mi)
            #pragma unroll
            for (int ni = 0; ni < 4; ++ni)
                acc[mi][ni] = __builtin_amdgcn_mfma_f32_16x16x32_bf16(Af[mi], Bf[ni], acc[mi][ni], 0, 0, 0);
        __syncthreads();
    }

    // ---- epilogue ----
    int L = lengths[b];
    int Leff = L > 5 ? L : 5;
    const int basew[6] = {0, 0, 1, 3, 6, 10};
    long sbase = (long)(((b * 4 + tt) * 16 + mtile) * 128) * 8;

    #pragma unroll 1
    for (int phase = 0; phase < 2; ++phase) {
        if (wm == phase) {
            // C/D layout: col = lane&15, row = quad*4 + reg  [verified m89/m91]
            #pragma unroll
            for (int mi = 0; mi < 4; ++mi)
                #pragma unroll
                for (int ni = 0; ni < 4; ++ni)
                    #pragma unroll
                    for (int r = 0; r < 4; ++r)
                        Gs[(mi * 16 + quad * 4 + r) * 129 + wn * 64 + ni * 16 + llo] = acc[mi][ni][r];
        }
        __syncthreads();
        // boundary strips: slots 0..3 = cols 0..3 (head), 4..7 = cols 124..127 (tail)
        {
            int row = tid >> 3, c = tid & 7;
            int col = (c < 4) ? c : (120 + c);
            #pragma unroll
            for (int rr = 0; rr < 2; ++rr) {
                int r2 = row + rr * 32;
                strips[sbase + (phase * 64 + r2) * 8 + c] = Gs[r2 * 129 + col];
            }
        }
        // pooling: wave wid handles filter group fl = wid of this phase
        {
            int fl = wid;
            int f = mtile * 8 + phase * 4 + fl;
            #pragma unroll
            for (int w = 1; w <= 5; ++w) {
                float bias = (w == 1 ? cb1 : w == 2 ? cb2 : w == 3 ? cb3 : w == 4 ? cb4 : cb5)[f];
                int limt = 128 - w;                    // complete-sum-in-tile bound
                int limv = Leff - w + 1 - tt * 128;    // validity bound (tile-local)
                float vmax = -1.f;
                #pragma unroll
                for (int half = 0; half < 2; ++half) {
                    int t = half * 64 + lane;
                    if (t <= limt && t < limv) {
                        float s = 0.f;
                        #pragma unroll
                        for (int j = 0; j < w; ++j)
                            s += Gs[(fl * 16 + basew[w] + j) * 129 + t + j];
                        s += bias;
                        s = fmaxf(s, 0.f);
                        vmax = fmaxf(vmax, s);
                    }
                }
                #pragma unroll
                for (int off = 32; off >= 1; off >>= 1)
                    vmax = fmaxf(vmax, __shfl_xor(vmax, off));
                if (lane == 0 && vmax >= 0.f)
                    atomicMax((int*)&pools[(b * 5 + (w - 1)) * NFC + f], __float_as_int(vmax));
            }
        }
        __syncthreads();
    }
}

// ---------------------------------------------------------------------------
// Kernel 2: boundary cleanup — pooled outputs whose conv window crosses a
// 128-col tile boundary (t_local in [129-w, 127], tiles 0..2), from strips.
// 256 blocks x 64 threads so all CUs participate (was 64 x 256).
// ---------------------------------------------------------------------------
__global__ void cleanup(const float* __restrict__ strips, const int* __restrict__ lengths,
                        const float* __restrict__ cb2, const float* __restrict__ cb3,
                        const float* __restrict__ cb4, const float* __restrict__ cb5,
                        float* __restrict__ pools) {
    int idx = blockIdx.x * 64 + threadIdx.x;  // 128*16*8 = 16384
    if (idx >= 16384) return;
    int b = idx >> 7;
    int mtile = (idx >> 3) & 15;
    int fl = idx & 7;
    int L = lengths[b];
    int Leff = L > 5 ? L : 5;
    int f = mtile * 8 + fl;
    const int basew[6] = {0, 0, 1, 3, 6, 10};
    for (int t2 = 0; t2 < 3; ++t2) {
        const float* s0 = strips + (long)(((b * 4 + t2) * 16 + mtile) * 128) * 8;
        const float* s1 = strips + (long)(((b * 4 + t2 + 1) * 16 + mtile) * 128) * 8;
        #pragma unroll
        for (int w = 2; w <= 5; ++w) {
            float bias = (w == 2 ? cb2 : w == 3 ? cb3 : w == 4 ? cb4 : cb5)[f];
            float best = -1.f;
            for (int t = 129 - w; t <= 127; ++t) {
                int tg = t2 * 128 + t;
                if (tg >= Leff - w + 1) continue;
                float s = 0.f;
                #pragma unroll
                for (int j = 0; j < w; ++j) {
                    int c = t + j;
                    int row = fl * 16 + basew[w] + j;
                    s += (c <= 127) ? s0[row * 8 + (c - 120)] : s1[row * 8 + (c - 128)];
                }
                s += bias;
                s = fmaxf(s, 0.f);
                best = fmaxf(best, s);
            }
            if (best >= 0.f)
                atomicMax((int*)&pools[(b * 5 + (w - 1)) * NFC + f], __float_as_int(best));
        }
    }
}

// ---------------------------------------------------------------------------
// Kernel 3: per-batch dot(feat, v) + c -> sigmoid.
// feat[b][k] = pools[b][w][f] with k = w*128+f (matches concat order).
// ---------------------------------------------------------------------------
__global__ void head(const float* __restrict__ pools, const float* __restrict__ v,
                     float* __restrict__ out) {
    int b = blockIdx.x;
    int tid = threadIdx.x;
    float s = 0.f;
    for (int k = tid; k < 640; k += 256) s += pools[b * 640 + k] * v[k];
    __shared__ float red[256];
    red[tid] = s;
    __syncthreads();
    for (int st = 128; st; st >>= 1) {
        if (tid < st) red[tid] += red[tid + st];
        __syncthreads();
    }
    if (tid == 0) out[b] = 1.f / (1.f + expf(-(red[0] + v[640])));
}

// ---------------------------------------------------------------------------
extern "C" void kernel_launch(void* const* d_in, const int* in_sizes, int n_in,
                              void* d_out, int out_size, void* d_ws, size_t ws_size,
                              hipStream_t stream) {
    const float* enc  = (const float*)d_in[0];
    const int* lens   = (const int*)d_in[1];
    const float* w1   = (const float*)d_in[2];
    const float* b1   = (const float*)d_in[3];
    const float* w2   = (const float*)d_in[4];
    const float* b2   = (const float*)d_in[5];
    const float* w3   = (const float*)d_in[6];
    const float* b3   = (const float*)d_in[7];
    const float* w4   = (const float*)d_in[8];
    const float* b4   = (const float*)d_in[9];
    const float* w5   = (const float*)d_in[10];
    const float* b5   = (const float*)d_in[11];
    const float* fc1w = (const float*)d_in[12];
    const float* fc1b = (const float*)d_in[13];
    const float* fc2w = (const float*)d_in[14];
    const float* fc2b = (const float*)d_in[15];
    float* out = (float*)d_out;

    // workspace layout
    unsigned short* Xg = (unsigned short*)d_ws;          // 33,554,432 ushorts (64 MB)
    unsigned short* Wg = Xg + 33554432;                  // 1,048,576 ushorts (2 MB)
    float* strips = (float*)(Wg + 1048576);              // 8,388,608 floats (32 MB)
    float* pools  = strips + 8388608;                    // 81,920 floats
    float* vbuf   = pools + 81920;                       // 641 floats

    prep<<<4417, 256, 0, stream>>>(w1, w2, w3, w4, w5, Wg, pools, fc1w, fc1b, fc2w, fc2b, vbuf);
    gather_x<<<8192, 256, 0, stream>>>(enc, lens, Xg);
    conv_gemm<<<8192, 256, 0, stream>>>(Wg, Xg, lens, b1, b2, b3, b4, b5, pools, strips);
    cleanup<<<256, 64, 0, stream>>>(strips, lens, b2, b3, b4, b5, pools);
    head<<<128, 256, 0, stream>>>(pools, vbuf, out);
}

// Round 3
// 419.622 us; speedup vs baseline: 1.1666x; 1.0663x over previous
//
#include <hip/hip_runtime.h>
#include <hip/hip_bf16.h>

// Problem constants
#define TT 512   // T
#define BB 128   // B
#define HH 512   // H
#define NFC 128  // NF
// FS = 5

typedef short v8s __attribute__((ext_vector_type(8)));
typedef float v4f __attribute__((ext_vector_type(4)));

__device__ __forceinline__ unsigned short f2bf(float x) {
    unsigned u = __float_as_uint(x);
    unsigned r = (u + 0x7fffu + ((u >> 16) & 1u)) >> 16;
    return (unsigned short)r;
}

// ---------------------------------------------------------------------------
// Kernel 0: fused prep + gather.
// blocks [0,8192): gather X_all, layout [n][h] bf16, n = b*512+l, row len 512.
//   X[b][h,l] = enc[(h*L+l)>>9, b, (h*L+l)&511] for l < L else 0.
//   Coalesced reads (l-contig) + LDS transpose + packed ushort4 writes.
//   Skip blocks whose 128-col tile is never consumed (tt*128 >= Leff).
// blocks [8192,12288): build stacked weight Wg, bf16, M=2048 x K=512.
//   s = f*16 + slice; slice in [0,15): (w,j) enumeration, slice 15 = pad.
// blocks [12288,12608): zero pools.
// block 12608: collapse fc2∘fc1 into v[640] + c (no act between them).
// ---------------------------------------------------------------------------
__global__ void prep_all(const float* __restrict__ enc, const int* __restrict__ lengths,
                         unsigned short* __restrict__ Xg,
                         const float* __restrict__ w1, const float* __restrict__ w2,
                         const float* __restrict__ w3, const float* __restrict__ w4,
                         const float* __restrict__ w5, unsigned short* __restrict__ Wg,
                         float* __restrict__ pools,
                         const float* __restrict__ fc1w, const float* __restrict__ fc1b,
                         const float* __restrict__ fc2w, const float* __restrict__ fc2b,
                         float* __restrict__ v) {
    int blk = blockIdx.x;
    int tid = threadIdx.x;
    if (blk < 8192) {
        __shared__ float tile[64 * 65];
        int b = blk >> 6;
        int lc = (blk >> 3) & 7;
        int hc = blk & 7;
        int L = lengths[b];
        int Leff = L > 5 ? L : 5;
        int l0 = lc * 64, h0 = hc * 64;
        if ((l0 & ~127) >= Leff) return;   // this 128-col tile is never consumed
        int lx = tid & 63;
        int hq = tid >> 6;                // 0..3
        #pragma unroll
        for (int r = 0; r < 16; ++r) {
            int hl = hq * 16 + r;         // local h
            int l = l0 + lx;
            float val = 0.f;
            if (l < L) {
                int i = (h0 + hl) * L + l;
                val = enc[(i >> 9) * (BB * HH) + b * HH + (i & 511)];
            }
            tile[hl * 65 + lx] = val;
        }
        __syncthreads();
        int hg = tid & 15;                // h quad within tile (4 bf16 = 8B)
        #pragma unroll
        for (int r = 0; r < 4; ++r) {
            int lloc = (tid >> 4) + r * 16;
            int n = b * 512 + l0 + lloc;
            ushort4 pk;
            pk.x = f2bf(tile[(hg * 4 + 0) * 65 + lloc]);
            pk.y = f2bf(tile[(hg * 4 + 1) * 65 + lloc]);
            pk.z = f2bf(tile[(hg * 4 + 2) * 65 + lloc]);
            pk.w = f2bf(tile[(hg * 4 + 3) * 65 + lloc]);
            *(ushort4*)&Xg[n * 512 + h0 + hg * 4] = pk;
        }
    } else if (blk < 12288) {
        int idx = (blk - 8192) * 256 + tid;   // 2048*512 = 1,048,576
        int s = idx >> 9, h = idx & 511;
        int f = s >> 4, sl = s & 15;
        float val = 0.f;
        if (sl < 15) {
            int w, j;
            if (sl < 1)       { w = 1; j = sl; }
            else if (sl < 3)  { w = 2; j = sl - 1; }
            else if (sl < 6)  { w = 3; j = sl - 3; }
            else if (sl < 10) { w = 4; j = sl - 6; }
            else              { w = 5; j = sl - 10; }
            const float* wp = (w == 1) ? w1 : (w == 2) ? w2 : (w == 3) ? w3 : (w == 4) ? w4 : w5;
            val = wp[f * (HH * w) + h * w + j];  // conv_w{w}[f,0,h,j]
        }
        Wg[idx] = f2bf(val);
    } else if (blk < 12608) {
        int i = (blk - 12288) * 256 + tid;
        if (i < BB * 5 * NFC) pools[i] = 0.f;
    } else {
        for (int k = tid; k < 640; k += 256) {
            float s = 0.f;
            for (int o = 0; o < 100; ++o) s += fc2w[o] * fc1w[o * 640 + k];
            v[k] = s;
        }
        if (tid == 0) {
            float c = fc2b[0];
            for (int o = 0; o < 100; ++o) c += fc2w[o] * fc1b[o];
            v[640] = c;
        }
    }
}

// ---------------------------------------------------------------------------
// Kernel 1: main fused GEMM + epilogue.
// Block tile: 128 (M) x 128 (N = t-range of one b), BK=64 (8 K-iterations,
// half the barrier drains of BK=32; A+B LDS = 32 KB aliased under the 33 KB
// epilogue Gs -> still 4 blocks/CU).
// Early exit if tile has no valid t (tt*128 >= Leff) — avg 37% of tiles.
// Swizzle: row of 8 16B-chunks, physical chunk p = q ^ (row&7). Staging
// permutes the GLOBAL address (LDS dest stays lane-contiguous, m104);
// fragment reads use p = (kh*4+quad) ^ (llo&7) -> conflict-free b128.
// ---------------------------------------------------------------------------
__global__ __launch_bounds__(256, 4)
void conv_gemm(const unsigned short* __restrict__ Wg, const unsigned short* __restrict__ Xg,
               const int* __restrict__ lengths,
               const float* __restrict__ cb1, const float* __restrict__ cb2,
               const float* __restrict__ cb3, const float* __restrict__ cb4,
               const float* __restrict__ cb5,
               float* __restrict__ pools, float* __restrict__ strips) {
    __shared__ __align__(16) char smem[64 * 129 * 4];       // 33024 B
    unsigned short* ldsA = (unsigned short*)smem;            // 16 KB (K-loop only)
    unsigned short* ldsB = (unsigned short*)(smem + 16384);  // 16 KB (K-loop only)
    float* Gs = (float*)smem;                                // 64*129 (epilogue only)

    int bi = blockIdx.x;                 // 8192 = 128 b * 16 mtile * 4 tt
    int b = bi >> 6;
    int mtile = (bi >> 2) & 15;
    int tt = bi & 3;
    int L = lengths[b];
    int Leff = L > 5 ? L : 5;
    if (tt * 128 >= Leff) return;        // no valid t in this tile for any w

    int tid = threadIdx.x;
    int wid = tid >> 6, lane = tid & 63;
    int wm = wid >> 1, wn = wid & 1;
    int llo = lane & 15, quad = lane >> 4;

    int m0 = mtile * 128;
    int nb0 = b * 512 + tt * 128;

    v4f acc[4][4];
    #pragma unroll
    for (int i = 0; i < 4; ++i)
        #pragma unroll
        for (int j = 0; j < 4; ++j) acc[i][j] = v4f{0.f, 0.f, 0.f, 0.f};

    // staging: wave wid covers rows [wid*32, wid*32+32): 4 insts of 8 rows per buffer
    int srow8 = lane >> 3;               // 0..7 (row within 8-row group)
    int gchunk = (lane & 7) ^ srow8;     // global chunk feeding physical slot lane&7
    const unsigned short* gA = Wg + (m0 + wid * 32 + srow8) * 512 + gchunk * 8;
    const unsigned short* gB = Xg + (nb0 + wid * 32 + srow8) * 512 + gchunk * 8;

    #pragma unroll 1
    for (int kt = 0; kt < 8; ++kt) {
        int ko = kt * 64;
        #pragma unroll
        for (int q = 0; q < 4; ++q) {
            __builtin_amdgcn_global_load_lds(
                (const __attribute__((address_space(1))) unsigned int*)(gA + q * (8 * 512) + ko),
                (__attribute__((address_space(3))) unsigned int*)&ldsA[(wid * 32 + q * 8) * 64],
                16, 0, 0);
            __builtin_amdgcn_global_load_lds(
                (const __attribute__((address_space(1))) unsigned int*)(gB + q * (8 * 512) + ko),
                (__attribute__((address_space(3))) unsigned int*)&ldsB[(wid * 32 + q * 8) * 64],
                16, 0, 0);
        }
        __syncthreads();
        #pragma unroll
        for (int kh = 0; kh < 2; ++kh) {
            int pk = (((kh * 4 + quad) ^ (llo & 7))) * 8;
            v8s Af[4], Bf[4];
            #pragma unroll
            for (int mi = 0; mi < 4; ++mi)
                Af[mi] = *(const v8s*)&ldsA[(wm * 64 + mi * 16 + llo) * 64 + pk];
            #pragma unroll
            for (int ni = 0; ni < 4; ++ni)
                Bf[ni] = *(const v8s*)&ldsB[(wn * 64 + ni * 16 + llo) * 64 + pk];
            #pragma unroll
            for (int mi = 0; mi < 4; ++mi)
                #pragma unroll
                for (int ni = 0; ni < 4; ++ni)
                    acc[mi][ni] = __builtin_amdgcn_mfma_f32_16x16x32_bf16(Af[mi], Bf[ni], acc[mi][ni], 0, 0, 0);
        }
        __syncthreads();
    }

    // ---- epilogue ----
    const int basew[6] = {0, 0, 1, 3, 6, 10};
    long sbase = (long)(((b * 4 + tt) * 16 + mtile) * 128) * 8;

    #pragma unroll 1
    for (int phase = 0; phase < 2; ++phase) {
        if (wm == phase) {
            // C/D layout: col = lane&15, row = quad*4 + reg  [verified m89/m91]
            #pragma unroll
            for (int mi = 0; mi < 4; ++mi)
                #pragma unroll
                for (int ni = 0; ni < 4; ++ni)
                    #pragma unroll
                    for (int r = 0; r < 4; ++r)
                        Gs[(mi * 16 + quad * 4 + r) * 129 + wn * 64 + ni * 16 + llo] = acc[mi][ni][r];
        }
        __syncthreads();
        // boundary strips: slots 0..3 = cols 0..3 (head), 4..7 = cols 124..127 (tail)
        {
            int row = tid >> 3, c = tid & 7;
            int col = (c < 4) ? c : (120 + c);
            #pragma unroll
            for (int rr = 0; rr < 2; ++rr) {
                int r2 = row + rr * 32;
                strips[sbase + (phase * 64 + r2) * 8 + c] = Gs[r2 * 129 + col];
            }
        }
        // pooling: wave wid handles filter group fl = wid of this phase
        {
            int fl = wid;
            int f = mtile * 8 + phase * 4 + fl;
            #pragma unroll
            for (int w = 1; w <= 5; ++w) {
                float bias = (w == 1 ? cb1 : w == 2 ? cb2 : w == 3 ? cb3 : w == 4 ? cb4 : cb5)[f];
                int limt = 128 - w;                    // complete-sum-in-tile bound
                int limv = Leff - w + 1 - tt * 128;    // validity bound (tile-local)
                float vmax = -1.f;
                #pragma unroll
                for (int half = 0; half < 2; ++half) {
                    int t = half * 64 + lane;
                    if (t <= limt && t < limv) {
                        float s = 0.f;
                        #pragma unroll
                        for (int j = 0; j < w; ++j)
                            s += Gs[(fl * 16 + basew[w] + j) * 129 + t + j];
                        s += bias;
                        s = fmaxf(s, 0.f);
                        vmax = fmaxf(vmax, s);
                    }
                }
                #pragma unroll
                for (int off = 32; off >= 1; off >>= 1)
                    vmax = fmaxf(vmax, __shfl_xor(vmax, off));
                if (lane == 0 && vmax >= 0.f)
                    atomicMax((int*)&pools[(b * 5 + (w - 1)) * NFC + f], __float_as_int(vmax));
            }
        }
        __syncthreads();
    }
}

// ---------------------------------------------------------------------------
// Kernel 2: boundary cleanup — pooled outputs whose conv window crosses a
// 128-col tile boundary (t_local in [129-w, 127], tiles 0..2), from strips.
// Any strip read here is from a processed tile: work at t2 requires
// Leff >= t2*128+129, which implies tiles t2 and t2+1 both ran.
// ---------------------------------------------------------------------------
__global__ void cleanup(const float* __restrict__ strips, const int* __restrict__ lengths,
                        const float* __restrict__ cb2, const float* __restrict__ cb3,
                        const float* __restrict__ cb4, const float* __restrict__ cb5,
                        float* __restrict__ pools) {
    int idx = blockIdx.x * 64 + threadIdx.x;  // 128*16*8 = 16384
    if (idx >= 16384) return;
    int b = idx >> 7;
    int mtile = (idx >> 3) & 15;
    int fl = idx & 7;
    int L = lengths[b];
    int Leff = L > 5 ? L : 5;
    int f = mtile * 8 + fl;
    const int basew[6] = {0, 0, 1, 3, 6, 10};
    for (int t2 = 0; t2 < 3; ++t2) {
        if (Leff < t2 * 128 + 129) break;   // no window crosses this boundary
        const float* s0 = strips + (long)(((b * 4 + t2) * 16 + mtile) * 128) * 8;
        const float* s1 = strips + (long)(((b * 4 + t2 + 1) * 16 + mtile) * 128) * 8;
        #pragma unroll
        for (int w = 2; w <= 5; ++w) {
            float bias = (w == 2 ? cb2 : w == 3 ? cb3 : w == 4 ? cb4 : cb5)[f];
            float best = -1.f;
            for (int t = 129 - w; t <= 127; ++t) {
                int tg = t2 * 128 + t;
                if (tg >= Leff - w + 1) continue;
                float s = 0.f;
                #pragma unroll
                for (int j = 0; j < w; ++j) {
                    int c = t + j;
                    int row = fl * 16 + basew[w] + j;
                    s += (c <= 127) ? s0[row * 8 + (c - 120)] : s1[row * 8 + (c - 128)];
                }
                s += bias;
                s = fmaxf(s, 0.f);
                best = fmaxf(best, s);
            }
            if (best >= 0.f)
                atomicMax((int*)&pools[(b * 5 + (w - 1)) * NFC + f], __float_as_int(best));
        }
    }
}

// ---------------------------------------------------------------------------
// Kernel 3: per-batch dot(feat, v) + c -> sigmoid.
// feat[b][k] = pools[b][w][f] with k = w*128+f (matches concat order).
// ---------------------------------------------------------------------------
__global__ void head(const float* __restrict__ pools, const float* __restrict__ v,
                     float* __restrict__ out) {
    int b = blockIdx.x;
    int tid = threadIdx.x;
    float s = 0.f;
    for (int k = tid; k < 640; k += 256) s += pools[b * 640 + k] * v[k];
    __shared__ float red[256];
    red[tid] = s;
    __syncthreads();
    for (int st = 128; st; st >>= 1) {
        if (tid < st) red[tid] += red[tid + st];
        __syncthreads();
    }
    if (tid == 0) out[b] = 1.f / (1.f + expf(-(red[0] + v[640])));
}

// ---------------------------------------------------------------------------
extern "C" void kernel_launch(void* const* d_in, const int* in_sizes, int n_in,
                              void* d_out, int out_size, void* d_ws, size_t ws_size,
                              hipStream_t stream) {
    const float* enc  = (const float*)d_in[0];
    const int* lens   = (const int*)d_in[1];
    const float* w1   = (const float*)d_in[2];
    const float* b1   = (const float*)d_in[3];
    const float* w2   = (const float*)d_in[4];
    const float* b2   = (const float*)d_in[5];
    const float* w3   = (const float*)d_in[6];
    const float* b3   = (const float*)d_in[7];
    const float* w4   = (const float*)d_in[8];
    const float* b4   = (const float*)d_in[9];
    const float* w5   = (const float*)d_in[10];
    const float* b5   = (const float*)d_in[11];
    const float* fc1w = (const float*)d_in[12];
    const float* fc1b = (const float*)d_in[13];
    const float* fc2w = (const float*)d_in[14];
    const float* fc2b = (const float*)d_in[15];
    float* out = (float*)d_out;

    // workspace layout
    unsigned short* Xg = (unsigned short*)d_ws;          // 33,554,432 ushorts (64 MB)
    unsigned short* Wg = Xg + 33554432;                  // 1,048,576 ushorts (2 MB)
    float* strips = (float*)(Wg + 1048576);              // 8,388,608 floats (32 MB)
    float* pools  = strips + 8388608;                    // 81,920 floats
    float* vbuf   = pools + 81920;                       // 641 floats

    prep_all<<<12609, 256, 0, stream>>>(enc, lens, Xg, w1, w2, w3, w4, w5, Wg, pools,
                                        fc1w, fc1b, fc2w, fc2b, vbuf);
    conv_gemm<<<8192, 256, 0, stream>>>(Wg, Xg, lens, b1, b2, b3, b4, b5, pools, strips);
    cleanup<<<256, 64, 0, stream>>>(strips, lens, b2, b3, b4, b5, pools);
    head<<<128, 256, 0, stream>>>(pools, vbuf, out);
}